// Round 4
// baseline (140.478 us; speedup 1.0000x reference)
//
#include <hip/hip_runtime.h>
#include <hip/hip_bf16.h>

// B=4, T=2048, SD=64, NE=4096, H=8, HS=8, FH=256. All reference reshapes are
// flat reinterpretations -> one flat buffer serves every "view".
// h/y/e flat element (t,l): b*131072 + t*64 + l.
// x viewed (B,SD,SD,T): b*4194304 + i*131072 + j*2048 + t.
// out viewed (B,SD,SD,T): b*8388608 + i*131072 + j*2048 + t.
// Softmax: shift-invariant; use fixed offset exp(qc-40) -> no global-max pass.

#define EPSF 1e-5f
#define OFFS 40.0f

// ------ K1: Feebler + LayerNorm1 + per-block column partial sums ------------
// Block (x=b+4*i fast-b, y=chunk): 256 threads, one float4 (4 cols of 1 row).
// b-fast so the 4 blocks sharing fw panel i are adjacent in dispatch -> L2/L3.
__global__ void K1(const float* __restrict__ x, const float* __restrict__ fw,
                   const float* __restrict__ g, const float* __restrict__ bia,
                   float* __restrict__ h, float* __restrict__ y,
                   float* __restrict__ part) {
    int xb = blockIdx.x;
    int b = xb & 3, i = xb >> 2;
    int t4 = blockIdx.y * 256 + threadIdx.x;    // float4 idx 0..511 in (b,i)
    const float4* x4 = (const float4*)x + (size_t)b * 2097152 + (size_t)i * 32768 + t4;
    const float4* f4 = (const float4*)fw + (size_t)i * 32768 + t4;
    float4 acc = make_float4(0.f, 0.f, 0.f, 0.f);
    #pragma unroll 8
    for (int j = 0; j < 64; ++j) {
        float4 xv = x4[(size_t)j * 512];
        float4 fv = f4[(size_t)j * 512];
        acc.x += xv.x * fv.x; acc.y += xv.y * fv.y;
        acc.z += xv.z * fv.z; acc.w += xv.w * fv.w;
    }
    // LN over 64-col row: 16 consecutive lanes per row (same wave).
    float s1 = acc.x + acc.y + acc.z + acc.w;
    float s2 = acc.x * acc.x + acc.y * acc.y + acc.z * acc.z + acc.w * acc.w;
    for (int off = 8; off; off >>= 1) {
        s1 += __shfl_xor(s1, off);
        s2 += __shfl_xor(s2, off);
    }
    float m = s1 * (1.f / 64.f);
    float var = s2 * (1.f / 64.f) - m * m;
    float rs = rsqrtf(var + EPSF);
    float4 gv = ((const float4*)g)[t4 & 15];
    float4 bv = ((const float4*)bia)[t4 & 15];
    float4 yv;
    yv.x = (acc.x - m) * rs * gv.x + bv.x;
    yv.y = (acc.y - m) * rs * gv.y + bv.y;
    yv.z = (acc.z - m) * rs * gv.z + bv.z;
    yv.w = (acc.w - m) * rs * gv.w + bv.w;
    size_t oidx = (size_t)b * 32768 + (size_t)i * 512 + t4;
    ((float4*)h)[oidx] = acc;
    ((float4*)y)[oidx] = yv;
    // per-block column partials (16 rows) via LDS atomics, then one write
    __shared__ float ysL[64];
    if (threadIdx.x < 64) ysL[threadIdx.x] = 0.f;
    __syncthreads();
    int c0 = (t4 & 15) * 4;
    atomicAdd(&ysL[c0 + 0], yv.x);
    atomicAdd(&ysL[c0 + 1], yv.y);
    atomicAdd(&ysL[c0 + 2], yv.z);
    atomicAdd(&ysL[c0 + 3], yv.w);
    __syncthreads();
    if (threadIdx.x < 64)
        part[(blockIdx.y * 256 + xb) * 64 + threadIdx.x] = ysL[threadIdx.x];
}

// ------ K1r: reduce partials -> ysum; ck = ysum@Wk, cv = ysum@Wv (tiny) -----
__global__ void K1r(const float* __restrict__ part, const float* __restrict__ wk,
                    const float* __restrict__ wv, float* __restrict__ ck,
                    float* __restrict__ cv) {
    __shared__ float ysL[256];
    int tid = threadIdx.x;
    int b = tid >> 6, c = tid & 63;
    float s = 0.f;
    for (int k = 0; k < 128; ++k) {
        int i = k & 63, yy = k >> 6;
        s += part[(yy * 256 + i * 4 + b) * 64 + c];
    }
    ysL[tid] = s;
    __syncthreads();
    int hh = c >> 3, d = c & 7;
    float a = 0.f, e = 0.f;
    for (int sdx = 0; sdx < 64; ++sdx) {
        float ys = ysL[b * 64 + sdx];
        a += ys * wk[hh * 512 + sdx * 8 + d];
        e += ys * wv[hh * 512 + sdx * 8 + d];
    }
    ck[tid] = a;
    cv[tid] = e;
}

// ------ K2: e = exp((y@Wq)*ck - OFFS), per-tile column expsum partials ------
// 16-row tiles, grid (4,128) = 512 blocks.
__global__ void K2(const float* __restrict__ y, const float* __restrict__ wq,
                   const float* __restrict__ ck, float* __restrict__ e,
                   float* __restrict__ esum) {
    __shared__ float yT[64][20];      // yT[s][r], 80B row stride (16B aligned)
    __shared__ float wqL[64][64];     // wqL[s][c]
    __shared__ float psum[4][64];
    int b = blockIdx.x, tile = blockIdx.y, t0 = tile * 16;
    int tid = threadIdx.x;
    for (int k = 0; k < 4; ++k) {
        int idx = k * 256 + tid;
        int r = idx >> 6, s = idx & 63;
        yT[s][r] = y[(size_t)b * 131072 + (size_t)(t0 + r) * 64 + s];
    }
    for (int k = 0; k < 16; ++k) {
        int idx = k * 256 + tid;
        int r = idx >> 6, cc = idx & 63;
        wqL[r][cc] = wq[(cc >> 3) * 512 + r * 8 + (cc & 7)];
    }
    __syncthreads();
    int c = tid & 63, tq = tid >> 6;
    float ckc = ck[b * 64 + c];
    float acc[4] = {0.f, 0.f, 0.f, 0.f};
    for (int s = 0; s < 64; ++s) {
        float w = wqL[s][c];
        float4 a0 = *(const float4*)&yT[s][tq * 4];
        acc[0] += a0.x * w; acc[1] += a0.y * w;
        acc[2] += a0.z * w; acc[3] += a0.w * w;
    }
    float ls = 0.f;
    #pragma unroll
    for (int k = 0; k < 4; ++k) {
        float v = __expf(acc[k] * ckc - OFFS);
        e[(size_t)b * 131072 + (size_t)(t0 + tq * 4 + k) * 64 + c] = v;
        ls += v;
    }
    psum[tq][c] = ls;
    __syncthreads();
    if (tid < 64)
        esum[(b * 128 + tile) * 64 + tid] =
            psum[0][tid] + psum[1][tid] + psum[2][tid] + psum[3][tid];
}

// ------ K4: proj+LN2+FFN (-> LDS hf) + fused Booster -> out -----------------
// Block (x=b fast, y=chunk 0..255): 8 t-rows = flat range [chunk*512,+512).
// b-fast so 4 b-blocks share the bw panel via L2/L3. 14KB LDS, 1024 blocks.
__global__ void K4(const float* __restrict__ h, const float* __restrict__ e,
                   const float* __restrict__ esum, const float* __restrict__ cv,
                   const float* __restrict__ projw, const float* __restrict__ projb,
                   const float* __restrict__ g2, const float* __restrict__ b2l,
                   const float* __restrict__ w1, const float* __restrict__ b1,
                   const float* __restrict__ w2, const float* __restrict__ fb2,
                   const float* __restrict__ bw, float* __restrict__ out) {
    __shared__ float2 pT[4][64];
    __shared__ float2 y2T[4][64];
    __shared__ float2 hidT[4][256];
    __shared__ float hfL[512];
    int b = blockIdx.x, chunk = blockIdx.y;
    int tid = threadIdx.x, l = tid & 63, w = tid >> 6;

    float den = 0.f;
    for (int t = 0; t < 128; ++t) den += esum[(b * 128 + t) * 64 + l];
    float scl = cv[b * 64 + l] / den;
    size_t base = (size_t)b * 131072 + (size_t)(chunk * 8 + w * 2) * 64 + l;

    float2 p;
    p.x = e[base] * scl;
    p.y = e[base + 64] * scl;
    pT[w][l] = p;
    __syncthreads();

    // proj
    float a0 = 0.f, a1 = 0.f;
    for (int c = 0; c < 64; ++c) {
        float2 pv = pT[w][c];
        float pw = projw[c * 64 + l];
        a0 += pv.x * pw; a1 += pv.y * pw;
    }
    float pb = projb[l], g2v = g2[l], b2v = b2l[l];
    float hmid[2], y2[2];
    hmid[0] = h[base] + a0 + pb;
    hmid[1] = h[base + 64] + a1 + pb;
    #pragma unroll
    for (int rr = 0; rr < 2; ++rr) {
        float v = hmid[rr];
        float s1 = v, s2 = v * v;
        for (int off = 32; off; off >>= 1) {
            s1 += __shfl_xor(s1, off);
            s2 += __shfl_xor(s2, off);
        }
        float mm = s1 * (1.f / 64.f);
        float var = s2 * (1.f / 64.f) - mm * mm;
        float rs = rsqrtf(var + EPSF);
        y2[rr] = (v - mm) * rs * g2v + b2v;
    }
    y2T[w][l] = make_float2(y2[0], y2[1]);
    __syncthreads();

    // FFN1
    float h1[4][2];
    #pragma unroll
    for (int u = 0; u < 4; ++u) {
        float bb = b1[u * 64 + l];
        h1[u][0] = bb; h1[u][1] = bb;
    }
    for (int s = 0; s < 64; ++s) {
        float2 yv = y2T[w][s];
        #pragma unroll
        for (int u = 0; u < 4; ++u) {
            float w1v = w1[s * 256 + u * 64 + l];
            h1[u][0] += yv.x * w1v;
            h1[u][1] += yv.y * w1v;
        }
    }
    #pragma unroll
    for (int u = 0; u < 4; ++u)
        hidT[w][u * 64 + l] = make_float2(fmaxf(h1[u][0], 0.f), fmaxf(h1[u][1], 0.f));
    __syncthreads();

    // FFN2 + residual -> hfL (local flat chunk of 512 floats)
    float c0 = 0.f, c1 = 0.f;
    #pragma unroll 4
    for (int jj = 0; jj < 256; ++jj) {
        float2 hv = hidT[w][jj];
        float w2v = w2[jj * 64 + l];
        c0 += hv.x * w2v; c1 += hv.y * w2v;
    }
    float fb = fb2[l];
    hfL[(w * 2 + 0) * 64 + l] = hmid[0] + c0 + fb;
    hfL[(w * 2 + 1) * 64 + l] = hmid[1] + c1 + fb;
    __syncthreads();

    // Booster: flat chunk -> (j, t-range); out[b,i,j,tr] = bw[i,j,tr] * hfL
    int jj = chunk >> 2;
    int tq4 = (chunk & 3) * 128;               // float4 offset within j-row
    int f4 = tid & 127, ig = tid >> 7;
    float4 hv = *(const float4*)&hfL[f4 * 4];
    const float4* bwp = (const float4*)bw + (size_t)jj * 512 + tq4 + f4;
    float4* op = (float4*)out + (size_t)b * 2097152 + (size_t)jj * 512 + tq4 + f4;
    for (int it = 0; it < 32; ++it) {
        int i = it * 2 + ig;
        float4 wv = bwp[(size_t)i * 32768];
        float4 ov;
        ov.x = wv.x * hv.x; ov.y = wv.y * hv.y;
        ov.z = wv.z * hv.z; ov.w = wv.w * hv.w;
        op[(size_t)i * 32768] = ov;
    }
}

extern "C" void kernel_launch(void* const* d_in, const int* in_sizes, int n_in,
                              void* d_out, int out_size, void* d_ws, size_t ws_size,
                              hipStream_t stream) {
    const float* x     = (const float*)d_in[0];
    const float* fw    = (const float*)d_in[1];
    const float* bw    = (const float*)d_in[2];
    const float* wq    = (const float*)d_in[3];
    const float* wk    = (const float*)d_in[4];
    const float* wv    = (const float*)d_in[5];
    const float* projw = (const float*)d_in[6];
    const float* projb = (const float*)d_in[7];
    const float* g1    = (const float*)d_in[8];
    const float* b1l   = (const float*)d_in[9];
    const float* g2    = (const float*)d_in[10];
    const float* b2l   = (const float*)d_in[11];
    const float* w1    = (const float*)d_in[12];
    const float* b1    = (const float*)d_in[13];
    const float* w2    = (const float*)d_in[14];
    const float* b2    = (const float*)d_in[15];
    float* out = (float*)d_out;

    float* wsf = (float*)d_ws;
    float* h    = wsf;                 // 524288
    float* y    = wsf + 524288;        // 524288
    float* e    = wsf + 1048576;       // 524288
    float* part = wsf + 1572864;       // 32768 (512 blocks x 64)
    float* esum = wsf + 1605632;       // 32768 (4 x 128 x 64)
    float* ck   = wsf + 1638400;       // 256
    float* cvb  = wsf + 1638656;       // 256

    K1 <<<dim3(256, 2), 256, 0, stream>>>(x, fw, g1, b1l, h, y, part);
    K1r<<<1, 256, 0, stream>>>(part, wk, wv, ck, cvb);
    K2 <<<dim3(4, 128), 256, 0, stream>>>(y, wq, ck, e, esum);
    K4 <<<dim3(4, 256), 256, 0, stream>>>(h, e, esum, cvb, projw, projb,
                                          g2, b2l, w1, b1, w2, b2, bw, out);
}